// Round 7
// baseline (447.901 us; speedup 1.0000x reference)
//
#include <hip/hip_runtime.h>

// BertSelfAttention: B=4 S=2048 D=1024 H=16 HD=64. Input buffers fp32 (runtime
// detected; bf16 fallback). detect -> convert to bf16 in ws -> qkv GEMM
// (Q pre-scaled by 0.125*log2e) -> flash attention:
//   - transposed scores; P straight from score regs (paired-tile k-remap)
//   - K A-frags DIRECT from global/L2 (no Ks LDS buffer; LDS 36.8->18.5 KB)
//   - mask rides the QK MFMA C-operand (no score FMA at all)
//   - V swizzled in LDS (stride 140) -> PV B-frag = 1 ds_read_b128
//   - row-sum l via MFMA with ones-B; native v_exp_f32; v_perm bf16 packing

typedef short bf16x4 __attribute__((ext_vector_type(4)));
typedef short bf16x8 __attribute__((ext_vector_type(8)));
typedef float f32x4 __attribute__((ext_vector_type(4)));

#define SEQ 2048
#define DIM 1024
#define NH 16
#define HDIM 64
#define QKV_ELEMS ((size_t)64 * SEQ * HDIM)

#define WS_FLAG  50331648ull
#define WS_XBF   50331904ull
#define WS_WBF   67109120ull
#define WS_BF32  73400576ull
#define WS_NEED  73412868ull

#define LOG2E 1.4426950408889634f
#define QSCALE (0.125f * LOG2E)

static __device__ __forceinline__ unsigned short f2bf(float f) {
  union { float f; unsigned u; } x; x.f = f;
  unsigned r = x.u + 0x7fffu + ((x.u >> 16) & 1u);
  return (unsigned short)(r >> 16);
}
static __device__ __forceinline__ float bf2f(unsigned short h) {
  union { unsigned u; float f; } x; x.u = ((unsigned)h) << 16;
  return x.f;
}
static __device__ __forceinline__ unsigned pk2bf(float a, float b) {
  union { float f; unsigned u; } x, y; x.f = a; y.f = b;
  return __builtin_amdgcn_perm(y.u + 0x8000u, x.u + 0x8000u, 0x07060302u);
}

template <bool FP32>
static __device__ __forceinline__ float load1(const void* p, size_t i) {
  if (FP32) return ((const float*)p)[i];
  else      return bf2f(((const unsigned short*)p)[i]);
}
template <bool FP32>
static __device__ __forceinline__ bf16x8 load8bf(const void* p, size_t i) {
  if (FP32) {
    f32x4 a = *(const f32x4*)((const float*)p + i);
    f32x4 b = *(const f32x4*)((const float*)p + i + 4);
    union { bf16x8 v; unsigned short u[8]; } r;
#pragma unroll
    for (int j = 0; j < 4; ++j) { r.u[j] = f2bf(a[j]); r.u[4 + j] = f2bf(b[j]); }
    return r.v;
  } else {
    return *(const bf16x8*)((const unsigned short*)p + i);
  }
}

// ---------------- dtype detector ----------------
__global__ void detect_dtype(const unsigned short* __restrict__ X, int* __restrict__ flag) {
  __shared__ int zc[256], bc[256];
  int z = 0, b = 0;
  for (int i = threadIdx.x; i < 16384; i += 256) {
    unsigned short u = X[2 * i];
    if (u == 0) z++;
    int e = (u >> 7) & 0xff;
    if (e >= 134) b++;
  }
  zc[threadIdx.x] = z; bc[threadIdx.x] = b;
  __syncthreads();
  for (int s = 128; s > 0; s >>= 1) {
    if (threadIdx.x < s) { zc[threadIdx.x] += zc[threadIdx.x + s]; bc[threadIdx.x] += bc[threadIdx.x + s]; }
    __syncthreads();
  }
  if (threadIdx.x == 0)
    *flag = (zc[0] > 8192 || bc[0] > 64) ? 1 : 0;   // 1 = fp32 buffers
}

// ---------------- convert inputs to bf16 (+ fp32 bias) ----------------
template <bool FP32>
__global__ void convert_all(const void* __restrict__ X,
                            const void* __restrict__ Wq, const void* __restrict__ Wk,
                            const void* __restrict__ Wv,
                            const void* __restrict__ bq, const void* __restrict__ bk,
                            const void* __restrict__ bv,
                            unsigned char* __restrict__ ws, const int* __restrict__ flag) {
  if (*flag != (FP32 ? 1 : 0)) return;
  unsigned short* Xb = (unsigned short*)(ws + WS_XBF);
  unsigned short* Wb = (unsigned short*)(ws + WS_WBF);
  float* Bb = (float*)(ws + WS_BF32);
  int blk = blockIdx.x;
  if (blk < 4096) {
    size_t base = ((size_t)blk * 256 + threadIdx.x) * 8;
    *(bf16x8*)(Xb + base) = load8bf<FP32>(X, base);
  } else if (blk < 5632) {
    int w = (blk - 4096) >> 9;
    int r = (blk - 4096) & 511;
    const void* W = (w == 0) ? Wq : (w == 1) ? Wk : Wv;
    size_t base = ((size_t)r * 256 + threadIdx.x) * 8;
    *(bf16x8*)(Wb + (size_t)w * 1048576 + base) = load8bf<FP32>(W, base);
  } else {
    int w = blk - 5632;
    const void* Bsrc = (w == 0) ? bq : (w == 1) ? bk : bv;
    for (int i = threadIdx.x; i < 1024; i += 256)
      Bb[w * 1024 + i] = load1<FP32>(Bsrc, i);
  }
}

// ---------------- QKV projection GEMM (bf16, padded-LDS staging) ------------
// Q outputs pre-scaled by QSCALE (score scale folded into projection).
#define XS_STRIDE 40
__global__ __launch_bounds__(256) void qkv_bf(
    const unsigned short* __restrict__ Xb, const unsigned short* __restrict__ Wb,
    const float* __restrict__ Bb,
    unsigned short* __restrict__ Qo, unsigned short* __restrict__ Ko,
    unsigned short* __restrict__ Vo)
{
  const int z = blockIdx.z;
  const unsigned short* W = Wb + (size_t)z * 1048576;

  __shared__ __align__(16) unsigned short Xs[128 * XS_STRIDE];
  __shared__ __align__(16) unsigned short Ws[128 * XS_STRIDE];

  const int tid  = threadIdx.x;
  const int wave = tid >> 6;
  const int lane = tid & 63;
  const int col  = lane & 15;
  const int quad = lane >> 4;
  const int wr = wave & 1;
  const int wc = wave >> 1;
  const int m0 = blockIdx.x * 128;
  const int n0 = blockIdx.y * 128;

  f32x4 zero4 = {0.f, 0.f, 0.f, 0.f};
  f32x4 acc[4][4];
#pragma unroll
  for (int i = 0; i < 4; ++i)
#pragma unroll
    for (int j = 0; j < 4; ++j) acc[i][j] = zero4;

  const int srow = tid >> 2;
  const int sseg = (tid & 3) << 3;

  for (int k0 = 0; k0 < DIM; k0 += 32) {
    __syncthreads();
#pragma unroll
    for (int a = 0; a < 2; ++a) {
      int r = a * 64 + srow;
      *(bf16x8*)(Xs + r * XS_STRIDE + sseg) = *(const bf16x8*)(Xb + (size_t)(m0 + r) * DIM + k0 + sseg);
      *(bf16x8*)(Ws + r * XS_STRIDE + sseg) = *(const bf16x8*)(W  + (size_t)(n0 + r) * DIM + k0 + sseg);
    }
    __syncthreads();

    bf16x8 Af[4], Bf[4];
#pragma unroll
    for (int i = 0; i < 4; ++i)
      Af[i] = *(const bf16x8*)(Xs + (wr * 64 + i * 16 + col) * XS_STRIDE + quad * 8);
#pragma unroll
    for (int j = 0; j < 4; ++j)
      Bf[j] = *(const bf16x8*)(Ws + (wc * 64 + j * 16 + col) * XS_STRIDE + quad * 8);
#pragma unroll
    for (int i = 0; i < 4; ++i)
#pragma unroll
      for (int j = 0; j < 4; ++j)
        acc[i][j] = __builtin_amdgcn_mfma_f32_16x16x32_bf16(Af[i], Bf[j], acc[i][j], 0, 0, 0);
  }

  const float oscale = (z == 0) ? QSCALE : 1.0f;
  if (z < 2) {
    unsigned short* Yo = (z == 0) ? Qo : Ko;
#pragma unroll
    for (int i = 0; i < 4; ++i) {
#pragma unroll
      for (int j = 0; j < 4; ++j) {
        int n = n0 + wc * 64 + j * 16 + col;
        float bvf = Bb[z * 1024 + n];
        int h = n >> 6, hd = n & 63;
#pragma unroll
        for (int r = 0; r < 4; ++r) {
          int m = m0 + wr * 64 + i * 16 + quad * 4 + r;
          int b = m >> 11, s = m & 2047;
          Yo[((size_t)(b * NH + h) * SEQ + s) * HDIM + hd] = f2bf((acc[i][j][r] + bvf) * oscale);
        }
      }
    }
  } else {
#pragma unroll
    for (int i = 0; i < 4; ++i) {
#pragma unroll
      for (int j = 0; j < 4; ++j) {
        int n = n0 + wc * 64 + j * 16 + col;
        float bvf = Bb[2 * 1024 + n];
        int h = n >> 6, hd = n & 63;
        int mbase = m0 + wr * 64 + i * 16 + quad * 4;
        int b = mbase >> 11, s = mbase & 2047;
        unsigned long long pk = 0;
#pragma unroll
        for (int r = 0; r < 4; ++r)
          pk |= (unsigned long long)f2bf(acc[i][j][r] + bvf) << (16 * r);
        *(unsigned long long*)(Vo + ((size_t)(b * NH + h) * HDIM + hd) * SEQ + s) = pk;
      }
    }
  }
}

// ---------------- fallback QKV (raw inputs, flag-gated) ----------------
template <bool FP32>
__global__ __launch_bounds__(256) void qkv_any(
    const void* __restrict__ X,
    const void* __restrict__ Wq, const void* __restrict__ bq,
    const void* __restrict__ Wk, const void* __restrict__ bk,
    const void* __restrict__ Wv, const void* __restrict__ bv,
    unsigned short* __restrict__ Qo, unsigned short* __restrict__ Ko,
    unsigned short* __restrict__ Vo, const int* __restrict__ flag)
{
  if (*flag != (FP32 ? 1 : 0)) return;
  const int z = blockIdx.z;
  const void* W    = (z == 0) ? Wq : (z == 1) ? Wk : Wv;
  const void* bias = (z == 0) ? bq : (z == 1) ? bk : bv;

  __shared__ __align__(16) unsigned short Xs[128 * XS_STRIDE];
  __shared__ __align__(16) unsigned short Ws[128 * XS_STRIDE];

  const int tid  = threadIdx.x;
  const int wave = tid >> 6;
  const int lane = tid & 63;
  const int col  = lane & 15;
  const int quad = lane >> 4;
  const int wr = wave & 1;
  const int wc = wave >> 1;
  const int m0 = blockIdx.x * 128;
  const int n0 = blockIdx.y * 128;

  f32x4 zero4 = {0.f, 0.f, 0.f, 0.f};
  f32x4 acc[4][4];
#pragma unroll
  for (int i = 0; i < 4; ++i)
#pragma unroll
    for (int j = 0; j < 4; ++j) acc[i][j] = zero4;

  const int srow = tid >> 2;
  const int sseg = (tid & 3) << 3;

  for (int k0 = 0; k0 < DIM; k0 += 32) {
    __syncthreads();
#pragma unroll
    for (int a = 0; a < 2; ++a) {
      int r = a * 64 + srow;
      *(bf16x8*)(Xs + r * XS_STRIDE + sseg) = load8bf<FP32>(X, (size_t)(m0 + r) * DIM + k0 + sseg);
      *(bf16x8*)(Ws + r * XS_STRIDE + sseg) = load8bf<FP32>(W, (size_t)(n0 + r) * DIM + k0 + sseg);
    }
    __syncthreads();

    bf16x8 Af[4], Bf[4];
#pragma unroll
    for (int i = 0; i < 4; ++i)
      Af[i] = *(const bf16x8*)(Xs + (wr * 64 + i * 16 + col) * XS_STRIDE + quad * 8);
#pragma unroll
    for (int j = 0; j < 4; ++j)
      Bf[j] = *(const bf16x8*)(Ws + (wc * 64 + j * 16 + col) * XS_STRIDE + quad * 8);
#pragma unroll
    for (int i = 0; i < 4; ++i)
#pragma unroll
      for (int j = 0; j < 4; ++j)
        acc[i][j] = __builtin_amdgcn_mfma_f32_16x16x32_bf16(Af[i], Bf[j], acc[i][j], 0, 0, 0);
  }

  const float oscale = (z == 0) ? QSCALE : 1.0f;
  if (z < 2) {
    unsigned short* Yo = (z == 0) ? Qo : Ko;
#pragma unroll
    for (int i = 0; i < 4; ++i) {
#pragma unroll
      for (int j = 0; j < 4; ++j) {
        int n = n0 + wc * 64 + j * 16 + col;
        float bvf = load1<FP32>(bias, n);
        int h = n >> 6, hd = n & 63;
#pragma unroll
        for (int r = 0; r < 4; ++r) {
          int m = m0 + wr * 64 + i * 16 + quad * 4 + r;
          int b = m >> 11, s = m & 2047;
          Yo[((size_t)(b * NH + h) * SEQ + s) * HDIM + hd] = f2bf((acc[i][j][r] + bvf) * oscale);
        }
      }
    }
  } else {
#pragma unroll
    for (int i = 0; i < 4; ++i) {
#pragma unroll
      for (int j = 0; j < 4; ++j) {
        int n = n0 + wc * 64 + j * 16 + col;
        float bvf = load1<FP32>(bias, n);
        int h = n >> 6, hd = n & 63;
        int mbase = m0 + wr * 64 + i * 16 + quad * 4;
        int b = mbase >> 11, s = mbase & 2047;
        unsigned long long pk = 0;
#pragma unroll
        for (int r = 0; r < 4; ++r)
          pk |= (unsigned long long)f2bf(acc[i][j][r] + bvf) << (16 * r);
        *(unsigned long long*)(Vo + ((size_t)(b * NH + h) * HDIM + hd) * SEQ + s) = pk;
      }
    }
  }
}

// ---------------- flash attention ----------------
// grid (32, 64), block 256; wave = 16 queries. Scores transposed (S^T).
// K A-frags direct from global (L2-hot). Mask rides the QK MFMA C operand.
// V swizzled: key=32p+16s+4q+r stored at pos=32p+8q+4s+r.
#define VST 140
template <bool FP32>
__global__ __launch_bounds__(256, 4) void attn_kernel(
    const unsigned short* __restrict__ Q,
    const unsigned short* __restrict__ K,
    const unsigned short* __restrict__ Vt,   // [bh][hd][SEQ]
    const void* __restrict__ mask,
    void* __restrict__ OutV, const int* __restrict__ flag)
{
  if (*flag != (FP32 ? 1 : 0)) return;

  __shared__ __align__(16) unsigned short Vs[64 * VST];
  __shared__ __align__(16) float Ms[128];

  const int tid  = threadIdx.x;
  const int wave = tid >> 6;
  const int lane = tid & 63;
  const int col  = lane & 15;
  const int quad = lane >> 4;
  const int qt = blockIdx.x;
  const int bh = blockIdx.y;
  const int b  = bh >> 4;
  const int h  = bh & 15;

  const unsigned short* Qb = Q  + (size_t)bh * SEQ * HDIM;
  const unsigned short* Kb = K  + (size_t)bh * SEQ * HDIM;
  const unsigned short* Vb = Vt + (size_t)bh * HDIM * SEQ;

  const int qrow = qt * 64 + wave * 16 + col;
  const bf16x8 Qf0 = *(const bf16x8*)(Qb + (size_t)qrow * HDIM + quad * 8);
  const bf16x8 Qf1 = *(const bf16x8*)(Qb + (size_t)qrow * HDIM + 32 + quad * 8);

  const f32x4 z4 = {0.f, 0.f, 0.f, 0.f};
  f32x4 Oacc[4];
  f32x4 Osum = z4;
#pragma unroll
  for (int t = 0; t < 4; ++t) Oacc[t] = z4;
  float mrun = -1e30f;

  union { bf16x8 v; unsigned u[4]; } ones;
#pragma unroll
  for (int i = 0; i < 4; ++i) ones.u[i] = 0x3F803F80u;   // bf16 1.0 x2

  // K frag pointer for this lane: row = col (within 16-row tile), seg = quad*8
  const unsigned short* Kl = Kb + (size_t)col * HDIM + quad * 8;

  for (int kt = 0; kt < 16; ++kt) {
    __syncthreads();
    {
#pragma unroll
      for (int a = 0; a < 4; ++a) {            // V^T 64 hd x 128 keys, swizzled
        int c = a * 256 + tid;
        int row = c >> 4, j = c & 15;
        union { bf16x8 v; bf16x4 h2[2]; } gv;
        gv.v = *(const bf16x8*)(Vb + (size_t)row * SEQ + kt * 128 + j * 8);
        int base = (j >> 2) * 32 + (j & 1) * 16 + ((j >> 1) & 1) * 4;
        *(bf16x4*)(Vs + row * VST + base) = gv.h2[0];
        *(bf16x4*)(Vs + row * VST + base + 8) = gv.h2[1];
      }
      if (tid < 128)
        Ms[tid] = load1<FP32>(mask, (size_t)b * SEQ + kt * 128 + tid) * LOG2E;
    }
    __syncthreads();

    // --- QK^T (S^T, log2 domain): C initialized with mask ---
    f32x4 st[8];
#pragma unroll
    for (int t = 0; t < 8; ++t) {
      const unsigned short* kp = Kl + (size_t)(kt * 128 + t * 16) * HDIM;
      bf16x8 Ka = *(const bf16x8*)(kp);
      bf16x8 Kc = *(const bf16x8*)(kp + 32);
      f32x4 d = *(const f32x4*)(Ms + t * 16 + quad * 4);   // mask*log2e as C
      d = __builtin_amdgcn_mfma_f32_16x16x32_bf16(Ka, Qf0, d, 0, 0, 0);
      d = __builtin_amdgcn_mfma_f32_16x16x32_bf16(Kc, Qf1, d, 0, 0, 0);
      st[t] = d;
    }

    // --- online softmax (per query = col; keys in-lane), native v_exp ---
    f32x4 m4 = st[0];
#pragma unroll
    for (int t = 1; t < 8; ++t)
#pragma unroll
      for (int r = 0; r < 4; ++r) m4[r] = fmaxf(m4[r], st[t][r]);
    float pm = fmaxf(fmaxf(m4[0], m4[1]), fmaxf(m4[2], m4[3]));
    pm = fmaxf(pm, __shfl_xor(pm, 16, 64));
    pm = fmaxf(pm, __shfl_xor(pm, 32, 64));
    float mn = fmaxf(mrun, pm);
    float alpha = __builtin_amdgcn_exp2f(mrun - mn);
    mrun = mn;
#pragma unroll
    for (int t = 0; t < 8; ++t)
#pragma unroll
      for (int r = 0; r < 4; ++r) st[t][r] = __builtin_amdgcn_exp2f(st[t][r] - mn);

    float av[4];
#pragma unroll
    for (int r = 0; r < 4; ++r) av[r] = __shfl(alpha, quad * 4 + r, 64);
#pragma unroll
    for (int t = 0; t < 4; ++t)
#pragma unroll
      for (int r = 0; r < 4; ++r) Oacc[t][r] *= av[r];
#pragma unroll
    for (int r = 0; r < 4; ++r) Osum[r] *= av[r];

    // --- PV + row-sum via MFMA; P straight from score regs ---
#pragma unroll
    for (int tp = 0; tp < 4; ++tp) {
      union { bf16x8 v; unsigned u[4]; } Af;
      Af.u[0] = pk2bf(st[2 * tp][0],     st[2 * tp][1]);
      Af.u[1] = pk2bf(st[2 * tp][2],     st[2 * tp][3]);
      Af.u[2] = pk2bf(st[2 * tp + 1][0], st[2 * tp + 1][1]);
      Af.u[3] = pk2bf(st[2 * tp + 1][2], st[2 * tp + 1][3]);
      Osum = __builtin_amdgcn_mfma_f32_16x16x32_bf16(Af.v, ones.v, Osum, 0, 0, 0);
#pragma unroll
      for (int t2 = 0; t2 < 4; ++t2) {
        bf16x8 Bv = *(const bf16x8*)(Vs + (t2 * 16 + col) * VST + tp * 32 + quad * 8);
        Oacc[t2] = __builtin_amdgcn_mfma_f32_16x16x32_bf16(Af.v, Bv, Oacc[t2], 0, 0, 0);
      }
    }
  }

  // epilogue: rows q = quad*4+r; l sits in Osum rows
  float liv[4];
#pragma unroll
  for (int r = 0; r < 4; ++r) liv[r] = 1.0f / Osum[r];
#pragma unroll
  for (int t2 = 0; t2 < 4; ++t2) {
#pragma unroll
    for (int r = 0; r < 4; ++r) {
      int q = qt * 64 + wave * 16 + quad * 4 + r;
      float v = Oacc[t2][r] * liv[r];
      v = (v == v) ? v : 0.0f;
      size_t oidx = ((size_t)b * SEQ + q) * DIM + h * HDIM + t2 * 16 + col;
      if (FP32) ((float*)OutV)[oidx] = v;
      else      ((unsigned short*)OutV)[oidx] = f2bf(v);
    }
  }
}

extern "C" void kernel_launch(void* const* d_in, const int* in_sizes, int n_in,
                              void* d_out, int out_size, void* d_ws, size_t ws_size,
                              hipStream_t stream) {
  const void* X    = d_in[0];
  const void* mask = d_in[1];
  const void* Wq   = d_in[2];
  const void* bq   = d_in[3];
  const void* Wk   = d_in[4];
  const void* bk   = d_in[5];
  const void* Wv   = d_in[6];
  const void* bv   = d_in[7];

  unsigned char* ws = (unsigned char*)d_ws;
  unsigned short* Qw = (unsigned short*)ws;
  unsigned short* Kw = Qw + QKV_ELEMS;
  unsigned short* Vw = Kw + QKV_ELEMS;
  int* flag = (int*)(ws + WS_FLAG);

  detect_dtype<<<1, 256, 0, stream>>>((const unsigned short*)X, flag);

  if (ws_size >= WS_NEED) {
    convert_all<false><<<5635, 256, 0, stream>>>(X, Wq, Wk, Wv, bq, bk, bv, ws, flag);
    convert_all<true ><<<5635, 256, 0, stream>>>(X, Wq, Wk, Wv, bq, bk, bv, ws, flag);
    qkv_bf<<<dim3(64, 8, 3), 256, 0, stream>>>(
        (const unsigned short*)(ws + WS_XBF), (const unsigned short*)(ws + WS_WBF),
        (const float*)(ws + WS_BF32), Qw, Kw, Vw);
  } else {
    qkv_any<false><<<dim3(64, 8, 3), 256, 0, stream>>>(X, Wq, bq, Wk, bk, Wv, bv, Qw, Kw, Vw, flag);
    qkv_any<true ><<<dim3(64, 8, 3), 256, 0, stream>>>(X, Wq, bq, Wk, bk, Wv, bv, Qw, Kw, Vw, flag);
  }

  attn_kernel<false><<<dim3(32, 64), 256, 0, stream>>>(Qw, Kw, Vw, mask, d_out, flag);
  attn_kernel<true ><<<dim3(32, 64), 256, 0, stream>>>(Qw, Kw, Vw, mask, d_out, flag);
}

// Round 9
// 309.807 us; speedup vs baseline: 1.4457x; 1.4457x over previous
//
#include <hip/hip_runtime.h>

// BertSelfAttention: B=4 S=2048 D=1024 H=16 HD=64. Input buffers fp32 (runtime
// detected; bf16 fallback). detect -> convert to bf16 in ws -> qkv GEMM
// (Q pre-scaled by 0.125*log2e; V written KEY-SWIZZLED per 32-key group:
//  key=32p+16s+4q+r stored at pos=32p+8q+4s+r -- free in the epilogue) ->
// flash attention:
//   - transposed scores; P straight from score regs (paired-tile k-remap)
//   - K,V staged via global_load_lds(16B) into XOR-seg-swizzled unpadded LDS
//     (glds16 copies verbatim; V's key order comes pre-swizzled from qkv)
//   - mask rides the QK MFMA C-operand
//   - row-sum l via MFMA with ones-B; native v_exp_f32; v_perm bf16 packing

typedef short bf16x4 __attribute__((ext_vector_type(4)));
typedef short bf16x8 __attribute__((ext_vector_type(8)));
typedef float f32x4 __attribute__((ext_vector_type(4)));

#define SEQ 2048
#define DIM 1024
#define NH 16
#define HDIM 64
#define QKV_ELEMS ((size_t)64 * SEQ * HDIM)

#define WS_FLAG  50331648ull
#define WS_XBF   50331904ull
#define WS_WBF   67109120ull
#define WS_BF32  73400576ull
#define WS_NEED  73412868ull

#define LOG2E 1.4426950408889634f
#define QSCALE (0.125f * LOG2E)

static __device__ __forceinline__ unsigned short f2bf(float f) {
  union { float f; unsigned u; } x; x.f = f;
  unsigned r = x.u + 0x7fffu + ((x.u >> 16) & 1u);
  return (unsigned short)(r >> 16);
}
static __device__ __forceinline__ float bf2f(unsigned short h) {
  union { unsigned u; float f; } x; x.u = ((unsigned)h) << 16;
  return x.f;
}
static __device__ __forceinline__ unsigned pk2bf(float a, float b) {
  union { float f; unsigned u; } x, y; x.f = a; y.f = b;
  return __builtin_amdgcn_perm(y.u + 0x8000u, x.u + 0x8000u, 0x07060302u);
}
// V key-swizzle for an aligned 4-key chunk base (s % 4 == 0)
static __device__ __forceinline__ int vswz(int s) {
  return (s & ~31) | (((s >> 2) & 3) << 3) | (((s >> 4) & 1) << 2);
}

template <bool FP32>
static __device__ __forceinline__ float load1(const void* p, size_t i) {
  if (FP32) return ((const float*)p)[i];
  else      return bf2f(((const unsigned short*)p)[i]);
}
template <bool FP32>
static __device__ __forceinline__ bf16x8 load8bf(const void* p, size_t i) {
  if (FP32) {
    f32x4 a = *(const f32x4*)((const float*)p + i);
    f32x4 b = *(const f32x4*)((const float*)p + i + 4);
    union { bf16x8 v; unsigned short u[8]; } r;
#pragma unroll
    for (int j = 0; j < 4; ++j) { r.u[j] = f2bf(a[j]); r.u[4 + j] = f2bf(b[j]); }
    return r.v;
  } else {
    return *(const bf16x8*)((const unsigned short*)p + i);
  }
}

// async global->LDS, 16B/lane; per-lane LDS dest = wave-uniform base + lane*16
static __device__ __forceinline__ void glds16(const unsigned short* g, unsigned short* l) {
  __builtin_amdgcn_global_load_lds(
      (const __attribute__((address_space(1))) unsigned int*)(unsigned long long)(const void*)g,
      (__attribute__((address_space(3))) unsigned int*)(unsigned int)(unsigned long long)(void*)l,
      16, 0, 0);
}

// ---------------- dtype detector ----------------
__global__ void detect_dtype(const unsigned short* __restrict__ X, int* __restrict__ flag) {
  __shared__ int zc[256], bc[256];
  int z = 0, b = 0;
  for (int i = threadIdx.x; i < 16384; i += 256) {
    unsigned short u = X[2 * i];
    if (u == 0) z++;
    int e = (u >> 7) & 0xff;
    if (e >= 134) b++;
  }
  zc[threadIdx.x] = z; bc[threadIdx.x] = b;
  __syncthreads();
  for (int s = 128; s > 0; s >>= 1) {
    if (threadIdx.x < s) { zc[threadIdx.x] += zc[threadIdx.x + s]; bc[threadIdx.x] += bc[threadIdx.x + s]; }
    __syncthreads();
  }
  if (threadIdx.x == 0)
    *flag = (zc[0] > 8192 || bc[0] > 64) ? 1 : 0;   // 1 = fp32 buffers
}

// ---------------- convert inputs to bf16 (+ fp32 bias) ----------------
template <bool FP32>
__global__ void convert_all(const void* __restrict__ X,
                            const void* __restrict__ Wq, const void* __restrict__ Wk,
                            const void* __restrict__ Wv,
                            const void* __restrict__ bq, const void* __restrict__ bk,
                            const void* __restrict__ bv,
                            unsigned char* __restrict__ ws, const int* __restrict__ flag) {
  if (*flag != (FP32 ? 1 : 0)) return;
  unsigned short* Xb = (unsigned short*)(ws + WS_XBF);
  unsigned short* Wb = (unsigned short*)(ws + WS_WBF);
  float* Bb = (float*)(ws + WS_BF32);
  int blk = blockIdx.x;
  if (blk < 4096) {
    size_t base = ((size_t)blk * 256 + threadIdx.x) * 8;
    *(bf16x8*)(Xb + base) = load8bf<FP32>(X, base);
  } else if (blk < 5632) {
    int w = (blk - 4096) >> 9;
    int r = (blk - 4096) & 511;
    const void* W = (w == 0) ? Wq : (w == 1) ? Wk : Wv;
    size_t base = ((size_t)r * 256 + threadIdx.x) * 8;
    *(bf16x8*)(Wb + (size_t)w * 1048576 + base) = load8bf<FP32>(W, base);
  } else {
    int w = blk - 5632;
    const void* Bsrc = (w == 0) ? bq : (w == 1) ? bk : bv;
    for (int i = threadIdx.x; i < 1024; i += 256)
      Bb[w * 1024 + i] = load1<FP32>(Bsrc, i);
  }
}

// ---------------- QKV projection GEMM (bf16, padded-LDS staging) ------------
#define XS_STRIDE 40
__global__ __launch_bounds__(256) void qkv_bf(
    const unsigned short* __restrict__ Xb, const unsigned short* __restrict__ Wb,
    const float* __restrict__ Bb,
    unsigned short* __restrict__ Qo, unsigned short* __restrict__ Ko,
    unsigned short* __restrict__ Vo)
{
  const int z = blockIdx.z;
  const unsigned short* W = Wb + (size_t)z * 1048576;

  __shared__ __align__(16) unsigned short Xs[128 * XS_STRIDE];
  __shared__ __align__(16) unsigned short Ws[128 * XS_STRIDE];

  const int tid  = threadIdx.x;
  const int wave = tid >> 6;
  const int lane = tid & 63;
  const int col  = lane & 15;
  const int quad = lane >> 4;
  const int wr = wave & 1;
  const int wc = wave >> 1;
  const int m0 = blockIdx.x * 128;
  const int n0 = blockIdx.y * 128;

  f32x4 zero4 = {0.f, 0.f, 0.f, 0.f};
  f32x4 acc[4][4];
#pragma unroll
  for (int i = 0; i < 4; ++i)
#pragma unroll
    for (int j = 0; j < 4; ++j) acc[i][j] = zero4;

  const int srow = tid >> 2;
  const int sseg = (tid & 3) << 3;

  for (int k0 = 0; k0 < DIM; k0 += 32) {
    __syncthreads();
#pragma unroll
    for (int a = 0; a < 2; ++a) {
      int r = a * 64 + srow;
      *(bf16x8*)(Xs + r * XS_STRIDE + sseg) = *(const bf16x8*)(Xb + (size_t)(m0 + r) * DIM + k0 + sseg);
      *(bf16x8*)(Ws + r * XS_STRIDE + sseg) = *(const bf16x8*)(W  + (size_t)(n0 + r) * DIM + k0 + sseg);
    }
    __syncthreads();

    bf16x8 Af[4], Bf[4];
#pragma unroll
    for (int i = 0; i < 4; ++i)
      Af[i] = *(const bf16x8*)(Xs + (wr * 64 + i * 16 + col) * XS_STRIDE + quad * 8);
#pragma unroll
    for (int j = 0; j < 4; ++j)
      Bf[j] = *(const bf16x8*)(Ws + (wc * 64 + j * 16 + col) * XS_STRIDE + quad * 8);
#pragma unroll
    for (int i = 0; i < 4; ++i)
#pragma unroll
      for (int j = 0; j < 4; ++j)
        acc[i][j] = __builtin_amdgcn_mfma_f32_16x16x32_bf16(Af[i], Bf[j], acc[i][j], 0, 0, 0);
  }

  const float oscale = (z == 0) ? QSCALE : 1.0f;
  if (z < 2) {
    unsigned short* Yo = (z == 0) ? Qo : Ko;
#pragma unroll
    for (int i = 0; i < 4; ++i) {
#pragma unroll
      for (int j = 0; j < 4; ++j) {
        int n = n0 + wc * 64 + j * 16 + col;
        float bvf = Bb[z * 1024 + n];
        int h = n >> 6, hd = n & 63;
#pragma unroll
        for (int r = 0; r < 4; ++r) {
          int m = m0 + wr * 64 + i * 16 + quad * 4 + r;
          int b = m >> 11, s = m & 2047;
          Yo[((size_t)(b * NH + h) * SEQ + s) * HDIM + hd] = f2bf((acc[i][j][r] + bvf) * oscale);
        }
      }
    }
  } else {
    // V: transposed [bh][hd][SEQ], KEY-SWIZZLED (4-key chunk -> vswz(s))
#pragma unroll
    for (int i = 0; i < 4; ++i) {
#pragma unroll
      for (int j = 0; j < 4; ++j) {
        int n = n0 + wc * 64 + j * 16 + col;
        float bvf = Bb[2 * 1024 + n];
        int h = n >> 6, hd = n & 63;
        int mbase = m0 + wr * 64 + i * 16 + quad * 4;
        int b = mbase >> 11, s = mbase & 2047;
        unsigned long long pk = 0;
#pragma unroll
        for (int r = 0; r < 4; ++r)
          pk |= (unsigned long long)f2bf(acc[i][j][r] + bvf) << (16 * r);
        *(unsigned long long*)(Vo + ((size_t)(b * NH + h) * HDIM + hd) * SEQ + vswz(s)) = pk;
      }
    }
  }
}

// ---------------- fallback QKV (raw inputs, flag-gated) ----------------
template <bool FP32>
__global__ __launch_bounds__(256) void qkv_any(
    const void* __restrict__ X,
    const void* __restrict__ Wq, const void* __restrict__ bq,
    const void* __restrict__ Wk, const void* __restrict__ bk,
    const void* __restrict__ Wv, const void* __restrict__ bv,
    unsigned short* __restrict__ Qo, unsigned short* __restrict__ Ko,
    unsigned short* __restrict__ Vo, const int* __restrict__ flag)
{
  if (*flag != (FP32 ? 1 : 0)) return;
  const int z = blockIdx.z;
  const void* W    = (z == 0) ? Wq : (z == 1) ? Wk : Wv;
  const void* bias = (z == 0) ? bq : (z == 1) ? bk : bv;

  __shared__ __align__(16) unsigned short Xs[128 * XS_STRIDE];
  __shared__ __align__(16) unsigned short Ws[128 * XS_STRIDE];

  const int tid  = threadIdx.x;
  const int wave = tid >> 6;
  const int lane = tid & 63;
  const int col  = lane & 15;
  const int quad = lane >> 4;
  const int wr = wave & 1;
  const int wc = wave >> 1;
  const int m0 = blockIdx.x * 128;
  const int n0 = blockIdx.y * 128;

  f32x4 zero4 = {0.f, 0.f, 0.f, 0.f};
  f32x4 acc[4][4];
#pragma unroll
  for (int i = 0; i < 4; ++i)
#pragma unroll
    for (int j = 0; j < 4; ++j) acc[i][j] = zero4;

  const int srow = tid >> 2;
  const int sseg = (tid & 3) << 3;

  for (int k0 = 0; k0 < DIM; k0 += 32) {
    __syncthreads();
#pragma unroll
    for (int a = 0; a < 2; ++a) {
      int r = a * 64 + srow;
      *(bf16x8*)(Xs + r * XS_STRIDE + sseg) = load8bf<FP32>(X, (size_t)(m0 + r) * DIM + k0 + sseg);
      *(bf16x8*)(Ws + r * XS_STRIDE + sseg) = load8bf<FP32>(W, (size_t)(n0 + r) * DIM + k0 + sseg);
    }
    __syncthreads();

    bf16x8 Af[4], Bf[4];
#pragma unroll
    for (int i = 0; i < 4; ++i)
      Af[i] = *(const bf16x8*)(Xs + (wr * 64 + i * 16 + col) * XS_STRIDE + quad * 8);
#pragma unroll
    for (int j = 0; j < 4; ++j)
      Bf[j] = *(const bf16x8*)(Ws + (wc * 64 + j * 16 + col) * XS_STRIDE + quad * 8);
#pragma unroll
    for (int i = 0; i < 4; ++i)
#pragma unroll
      for (int j = 0; j < 4; ++j)
        acc[i][j] = __builtin_amdgcn_mfma_f32_16x16x32_bf16(Af[i], Bf[j], acc[i][j], 0, 0, 0);
  }

  const float oscale = (z == 0) ? QSCALE : 1.0f;
  if (z < 2) {
    unsigned short* Yo = (z == 0) ? Qo : Ko;
#pragma unroll
    for (int i = 0; i < 4; ++i) {
#pragma unroll
      for (int j = 0; j < 4; ++j) {
        int n = n0 + wc * 64 + j * 16 + col;
        float bvf = load1<FP32>(bias, n);
        int h = n >> 6, hd = n & 63;
#pragma unroll
        for (int r = 0; r < 4; ++r) {
          int m = m0 + wr * 64 + i * 16 + quad * 4 + r;
          int b = m >> 11, s = m & 2047;
          Yo[((size_t)(b * NH + h) * SEQ + s) * HDIM + hd] = f2bf((acc[i][j][r] + bvf) * oscale);
        }
      }
    }
  } else {
#pragma unroll
    for (int i = 0; i < 4; ++i) {
#pragma unroll
      for (int j = 0; j < 4; ++j) {
        int n = n0 + wc * 64 + j * 16 + col;
        float bvf = load1<FP32>(bias, n);
        int h = n >> 6, hd = n & 63;
        int mbase = m0 + wr * 64 + i * 16 + quad * 4;
        int b = mbase >> 11, s = mbase & 2047;
        unsigned long long pk = 0;
#pragma unroll
        for (int r = 0; r < 4; ++r)
          pk |= (unsigned long long)f2bf(acc[i][j][r] + bvf) << (16 * r);
        *(unsigned long long*)(Vo + ((size_t)(b * NH + h) * HDIM + hd) * SEQ + vswz(s)) = pk;
      }
    }
  }
}

// ---------------- flash attention ----------------
// grid (32, 64), block 256; wave = 16 queries. Scores transposed (S^T).
// K LDS: 128 rows x 128B, 16B seg phys = logical ^ (row&7)  (glds16-staged)
// V LDS: 64 rows x 256B (keys pre-swizzled in ws), seg phys = logical ^ (row&15)
// Frag reads land on the 8-words/bank floor -> conflict-free.
template <bool FP32>
__global__ __launch_bounds__(256, 4) void attn_kernel(
    const unsigned short* __restrict__ Q,
    const unsigned short* __restrict__ K,
    const unsigned short* __restrict__ Vt,   // [bh][hd][SEQ], key-swizzled
    const void* __restrict__ mask,
    void* __restrict__ OutV, const int* __restrict__ flag)
{
  if (*flag != (FP32 ? 1 : 0)) return;

  __shared__ __align__(16) unsigned short Ks[128 * 64];
  __shared__ __align__(16) unsigned short Vs[64 * 128];
  __shared__ __align__(16) float Ms[128];

  const int tid  = threadIdx.x;
  const int wave = tid >> 6;
  const int lane = tid & 63;
  const int col  = lane & 15;
  const int quad = lane >> 4;
  const int qt = blockIdx.x;
  const int bh = blockIdx.y;
  const int b  = bh >> 4;
  const int h  = bh & 15;

  const unsigned short* Qb = Q  + (size_t)bh * SEQ * HDIM;
  const unsigned short* Kb = K  + (size_t)bh * SEQ * HDIM;
  const unsigned short* Vb = Vt + (size_t)bh * HDIM * SEQ;

  const int qrow = qt * 64 + wave * 16 + col;
  const bf16x8 Qf0 = *(const bf16x8*)(Qb + (size_t)qrow * HDIM + quad * 8);
  const bf16x8 Qf1 = *(const bf16x8*)(Qb + (size_t)qrow * HDIM + 32 + quad * 8);

  const f32x4 z4 = {0.f, 0.f, 0.f, 0.f};
  f32x4 Oacc[4];
  f32x4 Osum = z4;
#pragma unroll
  for (int t = 0; t < 4; ++t) Oacc[t] = z4;
  float mrun = -1e30f;

  union { bf16x8 v; unsigned u[4]; } ones;
#pragma unroll
  for (int i = 0; i < 4; ++i) ones.u[i] = 0x3F803F80u;   // bf16 1.0 x2

  const int krow_in = lane >> 3;            // 0..7
  const int kphys   = lane & 7;             // 16B seg within 128B row
  const int vrow_in = lane >> 4;            // 0..3
  const int vphys   = lane & 15;            // 16B seg within 256B row

  for (int kt = 0; kt < 16; ++kt) {
    __syncthreads();
    {
#pragma unroll
      for (int a = 0; a < 4; ++a) {         // K: 8 rows per glds16
        int row = wave * 32 + a * 8 + krow_in;
        int lseg = kphys ^ (row & 7);
        glds16(Kb + (size_t)(kt * 128 + row) * HDIM + lseg * 8,
               Ks + (wave * 32 + a * 8) * 64);
      }
#pragma unroll
      for (int a = 0; a < 4; ++a) {         // V: 4 rows per glds16
        int row = wave * 16 + a * 4 + vrow_in;
        int lseg = vphys ^ (row & 15);
        glds16(Vb + (size_t)row * SEQ + kt * 128 + lseg * 8,
               Vs + (wave * 16 + a * 4) * 128);
      }
      if (tid < 128)
        Ms[tid] = load1<FP32>(mask, (size_t)b * SEQ + kt * 128 + tid) * LOG2E;
    }
    __syncthreads();

    // --- QK^T (S^T, log2 domain): C initialized with mask ---
    f32x4 st[8];
#pragma unroll
    for (int t = 0; t < 8; ++t) {
      const unsigned short* kr = Ks + (t * 16 + col) * 64;
      bf16x8 Ka = *(const bf16x8*)(kr + (quad ^ (col & 7)) * 8);
      bf16x8 Kc = *(const bf16x8*)(kr + ((4 + quad) ^ (col & 7)) * 8);
      f32x4 d = *(const f32x4*)(Ms + t * 16 + quad * 4);   // mask*log2e as C
      d = __builtin_amdgcn_mfma_f32_16x16x32_bf16(Ka, Qf0, d, 0, 0, 0);
      d = __builtin_amdgcn_mfma_f32_16x16x32_bf16(Kc, Qf1, d, 0, 0, 0);
      st[t] = d;
    }

    // --- online softmax (per query = col; keys in-lane), native v_exp ---
    f32x4 m4 = st[0];
#pragma unroll
    for (int t = 1; t < 8; ++t)
#pragma unroll
      for (int r = 0; r < 4; ++r) m4[r] = fmaxf(m4[r], st[t][r]);
    float pm = fmaxf(fmaxf(m4[0], m4[1]), fmaxf(m4[2], m4[3]));
    pm = fmaxf(pm, __shfl_xor(pm, 16, 64));
    pm = fmaxf(pm, __shfl_xor(pm, 32, 64));
    float mn = fmaxf(mrun, pm);
    float alpha = __builtin_amdgcn_exp2f(mrun - mn);
    mrun = mn;
#pragma unroll
    for (int t = 0; t < 8; ++t)
#pragma unroll
      for (int r = 0; r < 4; ++r) st[t][r] = __builtin_amdgcn_exp2f(st[t][r] - mn);

    float av[4];
#pragma unroll
    for (int r = 0; r < 4; ++r) av[r] = __shfl(alpha, quad * 4 + r, 64);
#pragma unroll
    for (int t = 0; t < 4; ++t)
#pragma unroll
      for (int r = 0; r < 4; ++r) Oacc[t][r] *= av[r];
#pragma unroll
    for (int r = 0; r < 4; ++r) Osum[r] *= av[r];

    // --- PV + row-sum via MFMA; P straight from score regs ---
#pragma unroll
    for (int tp = 0; tp < 4; ++tp) {
      union { bf16x8 v; unsigned u[4]; } Af;
      Af.u[0] = pk2bf(st[2 * tp][0],     st[2 * tp][1]);
      Af.u[1] = pk2bf(st[2 * tp][2],     st[2 * tp][3]);
      Af.u[2] = pk2bf(st[2 * tp + 1][0], st[2 * tp + 1][1]);
      Af.u[3] = pk2bf(st[2 * tp + 1][2], st[2 * tp + 1][3]);
      Osum = __builtin_amdgcn_mfma_f32_16x16x32_bf16(Af.v, ones.v, Osum, 0, 0, 0);
#pragma unroll
      for (int t2 = 0; t2 < 4; ++t2) {
        bf16x8 Bv = *(const bf16x8*)(Vs + (t2 * 16 + col) * 128 + ((tp * 4 + quad) ^ col) * 8);
        Oacc[t2] = __builtin_amdgcn_mfma_f32_16x16x32_bf16(Af.v, Bv, Oacc[t2], 0, 0, 0);
      }
    }
  }

  // epilogue: rows q = quad*4+r; l sits in Osum rows
  float liv[4];
#pragma unroll
  for (int r = 0; r < 4; ++r) liv[r] = 1.0f / Osum[r];
#pragma unroll
  for (int t2 = 0; t2 < 4; ++t2) {
#pragma unroll
    for (int r = 0; r < 4; ++r) {
      int q = qt * 64 + wave * 16 + quad * 4 + r;
      float v = Oacc[t2][r] * liv[r];
      v = (v == v) ? v : 0.0f;
      size_t oidx = ((size_t)b * SEQ + q) * DIM + h * HDIM + t2 * 16 + col;
      if (FP32) ((float*)OutV)[oidx] = v;
      else      ((unsigned short*)OutV)[oidx] = f2bf(v);
    }
  }
}

extern "C" void kernel_launch(void* const* d_in, const int* in_sizes, int n_in,
                              void* d_out, int out_size, void* d_ws, size_t ws_size,
                              hipStream_t stream) {
  const void* X    = d_in[0];
  const void* mask = d_in[1];
  const void* Wq   = d_in[2];
  const void* bq   = d_in[3];
  const void* Wk   = d_in[4];
  const void* bk   = d_in[5];
  const void* Wv   = d_in[6];
  const void* bv   = d_in[7];

  unsigned char* ws = (unsigned char*)d_ws;
  unsigned short* Qw = (unsigned short*)ws;
  unsigned short* Kw = Qw + QKV_ELEMS;
  unsigned short* Vw = Kw + QKV_ELEMS;
  int* flag = (int*)(ws + WS_FLAG);

  detect_dtype<<<1, 256, 0, stream>>>((const unsigned short*)X, flag);

  if (ws_size >= WS_NEED) {
    convert_all<false><<<5635, 256, 0, stream>>>(X, Wq, Wk, Wv, bq, bk, bv, ws, flag);
    convert_all<true ><<<5635, 256, 0, stream>>>(X, Wq, Wk, Wv, bq, bk, bv, ws, flag);
    qkv_bf<<<dim3(64, 8, 3), 256, 0, stream>>>(
        (const unsigned short*)(ws + WS_XBF), (const unsigned short*)(ws + WS_WBF),
        (const float*)(ws + WS_BF32), Qw, Kw, Vw);
  } else {
    qkv_any<false><<<dim3(64, 8, 3), 256, 0, stream>>>(X, Wq, bq, Wk, bk, Wv, bv, Qw, Kw, Vw, flag);
    qkv_any<true ><<<dim3(64, 8, 3), 256, 0, stream>>>(X, Wq, bq, Wk, bk, Wv, bv, Qw, Kw, Vw, flag);
  }

  attn_kernel<false><<<dim3(32, 64), 256, 0, stream>>>(Qw, Kw, Vw, mask, d_out, flag);
  attn_kernel<true ><<<dim3(32, 64), 256, 0, stream>>>(Qw, Kw, Vw, mask, d_out, flag);
}